// Round 5
// baseline (762.794 us; speedup 1.0000x reference)
//
#include <hip/hip_runtime.h>
#include <math.h>

#define B_ 8192
#define F_ 16
#define V_ 50000
#define D_ 32
#define NE_ 3
#define EOD_ 512
#define M1_ 512
#define M2_ 256
#define M3_ 128
#define BE_ ((size_t)B_ * EOD_)

typedef __attribute__((ext_vector_type(8))) short short8;
typedef __attribute__((ext_vector_type(4))) float floatx4;

__device__ __forceinline__ unsigned short f2bf(float f) {
    union { float f; unsigned u; } v; v.f = f;
    unsigned r = v.u + 0x7FFF + ((v.u >> 16) & 1);
    return (unsigned short)(r >> 16);
}
__device__ __forceinline__ float bf2f(unsigned short h) {
    union { unsigned u; float f; } v; v.u = (unsigned)h << 16;
    return v.f;
}
// async global->LDS, 16B/lane; global addr per-lane, LDS dest wave-uniform base + lane*16
__device__ __forceinline__ void gld16(const void* g, void* l) {
    __builtin_amdgcn_global_load_lds(
        (const __attribute__((address_space(1))) unsigned int*)g,
        (__attribute__((address_space(3))) unsigned int*)l, 16, 0, 0);
}

// ---------------- embedding gather (fp32 tables -> bf16 es) ----------------
__global__ __launch_bounds__(256) void gather_k(const int* __restrict__ x,
    const float* __restrict__ tables, unsigned short* __restrict__ esb)
{
    int gid = blockIdx.x * 256 + threadIdx.x;
    int d8 = gid & 3;
    int f  = (gid >> 2) & 15;
    int b  = (gid >> 6) & (B_ - 1);
    int e  = gid >> 19;
    int idx = x[b * F_ + f] + f * V_;
    const float4* src = (const float4*)(tables + ((size_t)e * F_ * V_ + idx) * D_) + d8 * 2;
    float4 v0 = src[0], v1 = src[1];
    unsigned short o[8];
    o[0] = f2bf(v0.x); o[1] = f2bf(v0.y); o[2] = f2bf(v0.z); o[3] = f2bf(v0.w);
    o[4] = f2bf(v1.x); o[5] = f2bf(v1.y); o[6] = f2bf(v1.z); o[7] = f2bf(v1.w);
    unsigned short* dst = esb + ((size_t)e * B_ + b) * EOD_ + f * D_ + d8 * 8;
    *(uint4*)dst = *(uint4*)o;
}

// ------------- weight transpose+convert: fp32 W[K][N] -> bf16 Wt[N][K] -------------
__global__ __launch_bounds__(256) void wtrans12_k(const float* __restrict__ crossW,
    const float* __restrict__ mlp1W, unsigned short* __restrict__ Wt)
{
    __shared__ float tile[32][33];
    int bn = blockIdx.x * 32, bk = blockIdx.y * 32;
    int mat = blockIdx.z;
    const float* Wm = (mat < 9) ? crossW + (size_t)mat * 512 * 512
                                : mlp1W + (size_t)(mat - 9) * 512 * 512;
    unsigned short* Wtm = Wt + (size_t)mat * 512 * 512;
    int tx = threadIdx.x & 31, ty = threadIdx.x >> 5;
    #pragma unroll
    for (int i = 0; i < 32; i += 8)
        tile[ty + i][tx] = Wm[(size_t)(bk + ty + i) * 512 + bn + tx];
    __syncthreads();
    #pragma unroll
    for (int i = 0; i < 32; i += 8)
        Wtm[(size_t)(bn + ty + i) * 512 + bk + tx] = f2bf(tile[tx][ty + i]);
}

__global__ __launch_bounds__(256) void wtrans_k(const float* __restrict__ W,
    unsigned short* __restrict__ Wt, int K, int N)
{
    __shared__ float tile[32][33];
    int bn = blockIdx.x * 32, bk = blockIdx.y * 32;
    int tx = threadIdx.x & 31, ty = threadIdx.x >> 5;
    #pragma unroll
    for (int i = 0; i < 32; i += 8)
        tile[ty + i][tx] = W[(size_t)(bk + ty + i) * N + bn + tx];
    __syncthreads();
    #pragma unroll
    for (int i = 0; i < 32; i += 8)
        Wt[(size_t)(bn + ty + i) * K + bk + tx] = f2bf(tile[tx][ty + i]);
}

// ============ fused per-branch chain: 3 cross layers + mlp1, one block = 64 rows ============
// xl slab in LDS (chunk-major: [16 k-chunks][64 rows][32]), x0 + running xl in
// registers at C-fragment positions, weights staged 512x32 per k-iter via gld16.
__global__ __launch_bounds__(256, 1) void branch_k(
    const unsigned short* __restrict__ es,     // [3][B][512] bf16
    const unsigned short* __restrict__ Wall,   // [12][512][512] bf16 (9 cross + 3 mlp1), [n][k]
    const float* __restrict__ crossb,          // [3][3][512]
    const float* __restrict__ mlp1b,           // [3][512]
    unsigned short* __restrict__ outp)         // [3][B][512] bf16
{
    extern __shared__ unsigned short lds[];
    unsigned short* xs  = lds;           // 32768 shorts (64KB): xl slab
    unsigned short* Wst = lds + 32768;   // 16384 shorts (32KB): weight stage [512][32]

    const int t = threadIdx.x;
    const int w = t >> 6, lane = t & 63;
    const int quad = lane >> 4, lid = lane & 15;
    const int wrow = (w & 1) * 32, wcol = (w >> 1) * 256;
    const int e = blockIdx.y;
    const int rowbase = blockIdx.x * 64;
    const unsigned short* x0g = es + (size_t)e * BE_ + (size_t)rowbase * 512;

    // ---- stage x0 -> xs (chunk-major) ----
    #pragma unroll
    for (int g = 0; g < 16; g++) {
        int u = w * 16 + g, c = u >> 2, rb = u & 3;
        gld16(x0g + (size_t)(rb * 16 + (lane >> 2)) * 512 + c * 32 + (lane & 3) * 8,
              xs + c * 2048 + rb * 512 + lane * 8);
    }

    // ---- x0 (packed bf16) and running xl (fp32) at this thread's C positions ----
    unsigned x0p[2][16][2];
    float xlf[2][16][4];
    #pragma unroll
    for (int i = 0; i < 2; i++)
        #pragma unroll
        for (int j = 0; j < 16; j++) {
            int col = wcol + j * 16 + lid;
            int r0 = wrow + i * 16 + quad * 4;
            unsigned short v0 = x0g[(size_t)(r0 + 0) * 512 + col];
            unsigned short v1 = x0g[(size_t)(r0 + 1) * 512 + col];
            unsigned short v2 = x0g[(size_t)(r0 + 2) * 512 + col];
            unsigned short v3 = x0g[(size_t)(r0 + 3) * 512 + col];
            x0p[i][j][0] = (unsigned)v0 | ((unsigned)v1 << 16);
            x0p[i][j][1] = (unsigned)v2 | ((unsigned)v3 << 16);
            xlf[i][j][0] = bf2f(v0); xlf[i][j][1] = bf2f(v1);
            xlf[i][j][2] = bf2f(v2); xlf[i][j][3] = bf2f(v3);
        }

    floatx4 acc[2][16];

    // ================= 3 cross layers =================
    for (int l = 0; l < 3; l++) {
        const unsigned short* Wg = Wall + (size_t)(e * 3 + l) * 262144;
        const float* bp = crossb + ((size_t)e * 3 + l) * 512;
        float bv[16];
        #pragma unroll
        for (int j = 0; j < 16; j++) bv[j] = bp[wcol + j * 16 + lid];
        #pragma unroll
        for (int i = 0; i < 2; i++)
            #pragma unroll
            for (int j = 0; j < 16; j++) acc[i][j] = {0.f, 0.f, 0.f, 0.f};

        for (int k0 = 0; k0 < 512; k0 += 32) {
            __syncthreads();                     // Ws reuse + xs-write visibility
            #pragma unroll
            for (int g = 0; g < 8; g++) {
                int rb = w * 8 + g;
                gld16(Wg + (size_t)(rb * 16 + (lane >> 2)) * 512 + k0 + (lane & 3) * 8,
                      Wst + rb * 512 + lane * 8);
            }
            __syncthreads();
            int c = k0 >> 5;
            short8 af0 = *(const short8*)(xs + c * 2048 + (wrow + 0 + lid) * 32 + quad * 8);
            short8 af1 = *(const short8*)(xs + c * 2048 + (wrow + 16 + lid) * 32 + quad * 8);
            #pragma unroll
            for (int j = 0; j < 16; j++) {
                short8 bfv = *(const short8*)(Wst + (wcol + j * 16 + lid) * 32 + quad * 8);
                acc[0][j] = __builtin_amdgcn_mfma_f32_16x16x32_bf16(af0, bfv, acc[0][j], 0, 0, 0);
                acc[1][j] = __builtin_amdgcn_mfma_f32_16x16x32_bf16(af1, bfv, acc[1][j], 0, 0, 0);
            }
        }
        __syncthreads();                         // all A-reads done before xs overwrite

        // epilogue: xl_new = x0 * (acc + b) + xl ; update regs + slab
        #pragma unroll
        for (int i = 0; i < 2; i++)
            #pragma unroll
            for (int j = 0; j < 16; j++) {
                int col = wcol + j * 16 + lid;
                int cbase = (col >> 5) * 2048 + (col & 31);
                int r0 = wrow + i * 16 + quad * 4;
                #pragma unroll
                for (int rr = 0; rr < 4; rr++) {
                    float x0v = bf2f((unsigned short)((x0p[i][j][rr >> 1] >> ((rr & 1) * 16)) & 0xFFFF));
                    float nv = x0v * (acc[i][j][rr] + bv[j]) + xlf[i][j][rr];
                    xlf[i][j][rr] = nv;
                    xs[cbase + (r0 + rr) * 32] = f2bf(nv);
                }
            }
    }

    // ================= mlp1: h = relu(xl @ W + b) / 3 =================
    {
        const unsigned short* Wg = Wall + (size_t)(9 + e) * 262144;
        const float* bp = mlp1b + (size_t)e * 512;
        float bv[16];
        #pragma unroll
        for (int j = 0; j < 16; j++) bv[j] = bp[wcol + j * 16 + lid];
        #pragma unroll
        for (int i = 0; i < 2; i++)
            #pragma unroll
            for (int j = 0; j < 16; j++) acc[i][j] = {0.f, 0.f, 0.f, 0.f};

        for (int k0 = 0; k0 < 512; k0 += 32) {
            __syncthreads();
            #pragma unroll
            for (int g = 0; g < 8; g++) {
                int rb = w * 8 + g;
                gld16(Wg + (size_t)(rb * 16 + (lane >> 2)) * 512 + k0 + (lane & 3) * 8,
                      Wst + rb * 512 + lane * 8);
            }
            __syncthreads();
            int c = k0 >> 5;
            short8 af0 = *(const short8*)(xs + c * 2048 + (wrow + 0 + lid) * 32 + quad * 8);
            short8 af1 = *(const short8*)(xs + c * 2048 + (wrow + 16 + lid) * 32 + quad * 8);
            #pragma unroll
            for (int j = 0; j < 16; j++) {
                short8 bfv = *(const short8*)(Wst + (wcol + j * 16 + lid) * 32 + quad * 8);
                acc[0][j] = __builtin_amdgcn_mfma_f32_16x16x32_bf16(af0, bfv, acc[0][j], 0, 0, 0);
                acc[1][j] = __builtin_amdgcn_mfma_f32_16x16x32_bf16(af1, bfv, acc[1][j], 0, 0, 0);
            }
        }
        __syncthreads();
        // write result row-major into xs, then vectorized copy-out
        #pragma unroll
        for (int i = 0; i < 2; i++)
            #pragma unroll
            for (int j = 0; j < 16; j++) {
                int col = wcol + j * 16 + lid;
                int r0 = wrow + i * 16 + quad * 4;
                #pragma unroll
                for (int rr = 0; rr < 4; rr++) {
                    float v = fmaxf(acc[i][j][rr] + bv[j], 0.f) * (1.f / 3.f);
                    xs[(r0 + rr) * 512 + col] = f2bf(v);
                }
            }
        __syncthreads();
        unsigned short* dst = outp + (size_t)e * BE_ + (size_t)rowbase * 512;
        #pragma unroll
        for (int g = 0; g < 16; g++) {
            int u = g * 256 + t;
            *(uint4*)(dst + u * 8) = *(const uint4*)(xs + u * 8);
        }
    }
}

// ---------------- bf16 MFMA GEMM (for the shared MLP tail), 128x128 tile ----------------
__global__ __launch_bounds__(256) void gemm_mfma_k(
    const unsigned short* __restrict__ A,
    const unsigned short* __restrict__ Wt,
    const float* __restrict__ bias,
    unsigned short* __restrict__ outb,
    int M, int N, int K)
{
    __shared__ unsigned short As[128 * 32];
    __shared__ unsigned short Bs[128 * 32];
    int t = threadIdx.x;
    int w = t >> 6, lane = t & 63;
    int quad = lane >> 4, lid = lane & 15;
    int wr = (w & 1) * 64, wc = (w >> 1) * 64;
    int rowbase = blockIdx.y * 128, colbase = blockIdx.x * 128;

    int chunk = w * 2;
    int sub = lane >> 2;
    int kk = (lane & 3) * 8;
    const unsigned short* pa0 = A  + (size_t)(rowbase + chunk * 16 + sub) * K + kk;
    const unsigned short* pa1 = pa0 + (size_t)16 * K;
    const unsigned short* pb0 = Wt + (size_t)(colbase + chunk * 16 + sub) * K + kk;
    const unsigned short* pb1 = pb0 + (size_t)16 * K;
    unsigned short* la0 = As + chunk * 512 + lane * 8;
    unsigned short* la1 = la0 + 512;
    unsigned short* lb0 = Bs + chunk * 512 + lane * 8;
    unsigned short* lb1 = lb0 + 512;

    floatx4 acc[4][4];
    #pragma unroll
    for (int i = 0; i < 4; i++)
        #pragma unroll
        for (int j = 0; j < 4; j++) acc[i][j] = {0.f, 0.f, 0.f, 0.f};

    for (int k0 = 0; k0 < K; k0 += 32) {
        if (k0) __syncthreads();
        gld16(pa0 + k0, la0);
        gld16(pa1 + k0, la1);
        gld16(pb0 + k0, lb0);
        gld16(pb1 + k0, lb1);
        __syncthreads();
        short8 af[4], bfr[4];
        #pragma unroll
        for (int i = 0; i < 4; i++) {
            af[i]  = *(const short8*)(As + (wr + i * 16 + lid) * 32 + quad * 8);
            bfr[i] = *(const short8*)(Bs + (wc + i * 16 + lid) * 32 + quad * 8);
        }
        #pragma unroll
        for (int i = 0; i < 4; i++)
            #pragma unroll
            for (int j = 0; j < 4; j++)
                acc[i][j] = __builtin_amdgcn_mfma_f32_16x16x32_bf16(af[i], bfr[j], acc[i][j], 0, 0, 0);
    }

    #pragma unroll
    for (int i = 0; i < 4; i++) {
        int row0 = rowbase + wr + i * 16 + quad * 4;
        #pragma unroll
        for (int j = 0; j < 4; j++) {
            int col = colbase + wc + j * 16 + lid;
            float bv = bias[col];
            #pragma unroll
            for (int rr = 0; rr < 4; rr++) {
                size_t off = (size_t)(row0 + rr) * N + col;
                outb[off] = f2bf(fmaxf(acc[i][j][rr] + bv, 0.f));
            }
        }
    }
}

// ---------------- sum of 3 per-e mlp1 outputs (bf16) ----------------
__global__ __launch_bounds__(256) void sum3_k(const unsigned short* __restrict__ h,
                                              unsigned short* __restrict__ o)
{
    size_t i = ((size_t)blockIdx.x * 256 + threadIdx.x) * 8;
    uint4 a = *(const uint4*)(h + i);
    uint4 b = *(const uint4*)(h + BE_ + i);
    uint4 c = *(const uint4*)(h + 2 * BE_ + i);
    const unsigned short* pa = (const unsigned short*)&a;
    const unsigned short* pb = (const unsigned short*)&b;
    const unsigned short* pc = (const unsigned short*)&c;
    unsigned short r[8];
    #pragma unroll
    for (int j = 0; j < 8; j++) r[j] = f2bf(bf2f(pa[j]) + bf2f(pb[j]) + bf2f(pc[j]));
    *(uint4*)(o + i) = *(uint4*)r;
}

// ---------------- final 128->1 dot + sigmoid (bf16 h2) ----------------
__global__ __launch_bounds__(256) void final_k(const unsigned short* __restrict__ h2,
    const float* __restrict__ W3, const float* __restrict__ b3,
    float* __restrict__ out)
{
    int gt = blockIdx.x * 256 + threadIdx.x;
    int s = gt >> 6, lane = gt & 63;
    float p = bf2f(h2[(size_t)s * 128 + lane]) * W3[lane]
            + bf2f(h2[(size_t)s * 128 + 64 + lane]) * W3[64 + lane];
    #pragma unroll
    for (int off = 32; off > 0; off >>= 1) p += __shfl_down(p, off);
    if (lane == 0) out[s] = 1.0f / (1.0f + expf(-(p + b3[0])));
}

// ---------------- pair Gram accumulation (bf16 in, fp32 accum) ----------------
__global__ __launch_bounds__(256) void pairsum_k(const unsigned short* __restrict__ es,
                                                 float* __restrict__ m)
{
    const int pi[3] = {1, 2, 2};
    const int pj[3] = {0, 0, 1};
    int pk = blockIdx.x;
    int pair = pk >> 4, k = pk & 15;
    const unsigned short* Ei = es + (size_t)pi[pair] * BE_ + k * D_;
    const unsigned short* Ej = es + (size_t)pj[pair] * BE_ + k * D_;
    int b0 = blockIdx.y * (B_ / 16);

    __shared__ float sa[8][32], sb[8][32];
    int t = threadIdx.x;
    int d = t >> 3, e4 = (t & 7) * 4;
    int lr = t >> 5, lc = t & 31;
    float a0 = 0, a1 = 0, a2 = 0, a3 = 0;

    for (int bb = b0; bb < b0 + B_ / 16; bb += 8) {
        __syncthreads();
        sa[lr][lc] = bf2f(Ei[(size_t)(bb + lr) * EOD_ + lc]);
        sb[lr][lc] = bf2f(Ej[(size_t)(bb + lr) * EOD_ + lc]);
        __syncthreads();
        #pragma unroll
        for (int s2 = 0; s2 < 8; s2++) {
            float avv = sa[s2][d];
            float4 bvv = *(const float4*)&sb[s2][e4];
            a0 += avv * bvv.x; a1 += avv * bvv.y;
            a2 += avv * bvv.z; a3 += avv * bvv.w;
        }
    }
    float* dst = m + (size_t)pk * 1024 + d * 32 + e4;
    atomicAdd(dst + 0, a0); atomicAdd(dst + 1, a1);
    atomicAdd(dst + 2, a2); atomicAdd(dst + 3, a3);
}

// ---------------- 32x32 singular values: one-sided Jacobi, register-resident ----------------
__global__ __launch_bounds__(64) void svd_k(const float* __restrict__ mg,
                                            float* __restrict__ sv)
{
    int mat = blockIdx.x;
    int l = threadIdx.x;
    int col = l & 31, half = l >> 5;
    const float* src = mg + (size_t)mat * 1024 + half * 16 * 32 + col;
    float a[16];
    #pragma unroll
    for (int j = 0; j < 16; j++) a[j] = src[j * 32];

    for (int sweep = 0; sweep < 6; sweep++) {
        for (int r = 0; r < 31; r++) {
            int partner, isp;
            if (col == 31) { partner = r; isp = 1; }
            else {
                int u = col - r; if (u < 0) u += 31;
                if (u == 0) { partner = 31; isp = 0; }
                else {
                    int v = 2 * r - col; v %= 31; if (v < 0) v += 31;
                    partner = v;
                    isp = (u <= 15) ? 1 : 0;
                }
            }
            int plane = half * 32 + partner;
            float b[16];
            #pragma unroll
            for (int j = 0; j < 16; j++) b[j] = __shfl(a[j], plane, 64);
            float own = 0.f, cross = 0.f, par = 0.f;
            #pragma unroll
            for (int j = 0; j < 16; j++) {
                own   += a[j] * a[j];
                cross += a[j] * b[j];
                par   += b[j] * b[j];
            }
            own   += __shfl_xor(own, 32);
            cross += __shfl_xor(cross, 32);
            par   += __shfl_xor(par, 32);
            float app = isp ? own : par;
            float aqq = isp ? par : own;
            float c = 1.f, s = 0.f;
            if (fabsf(cross) > 1e-12f) {
                float tau = (aqq - app) / (2.f * cross);
                float tt = (tau >= 0.f) ? 1.f / (tau + sqrtf(1.f + tau * tau))
                                        : 1.f / (tau - sqrtf(1.f + tau * tau));
                c = rsqrtf(1.f + tt * tt); s = tt * c;
            }
            float sgn = isp ? -s : s;
            #pragma unroll
            for (int j = 0; j < 16; j++) a[j] = c * a[j] + sgn * b[j];
        }
    }

    float nn = 0.f;
    #pragma unroll
    for (int j = 0; j < 16; j++) nn += a[j] * a[j];
    nn += __shfl_xor(nn, 32);
    float v = sqrtf(nn);

    __shared__ float ev[32];
    if (half == 0) ev[col] = v;
    if (half == 0) {
        int rank = 0;
        for (int o2 = 0; o2 < 32; o2++) {
            float w = ev[o2];
            if (w > v || (w == v && o2 < col)) rank++;
        }
        sv[(size_t)mat * 32 + rank] = v;
    }
}

// ---------------- reg loss reduction ----------------
__global__ __launch_bounds__(128) void reg_k(const float* __restrict__ sv,
                                             float* __restrict__ out)
{
    __shared__ float red[128];
    int t = threadIdx.x;
    float val = 0.f;
    if (t < 96) {
        int p = t >> 5, d = t & 31;
        float s = 0;
        #pragma unroll
        for (int k = 0; k < 16; k++) s += sv[(size_t)(p * 16 + k) * 32 + d];
        s *= (1.f / 16.f);
        val = s * s;
    }
    red[t] = val; __syncthreads();
    for (int off = 64; off > 0; off >>= 1) {
        if (t < off) red[t] += red[t + off];
        __syncthreads();
    }
    if (t == 0) out[B_] = 0.01f * red[0] / 96.f;
}

extern "C" void kernel_launch(void* const* d_in, const int* in_sizes, int n_in,
                              void* d_out, int out_size, void* d_ws, size_t ws_size,
                              hipStream_t stream)
{
    const int*   x      = (const int*)d_in[0];
    const float* emb    = (const float*)d_in[1];
    const float* crossW = (const float*)d_in[2];
    const float* crossb = (const float*)d_in[3];
    const float* mlp1W  = (const float*)d_in[4];
    const float* mlp1b  = (const float*)d_in[5];
    const float* W1     = (const float*)d_in[6];
    const float* b1     = (const float*)d_in[7];
    const float* W2     = (const float*)d_in[8];
    const float* b2     = (const float*)d_in[9];
    const float* W3     = (const float*)d_in[10];
    const float* b3     = (const float*)d_in[11];
    float* out = (float*)d_out;

    unsigned char* wsb = (unsigned char*)d_ws;
    size_t o = 0;
    auto alloc = [&](size_t bytes) -> void* {
        void* p = wsb + o; o += (bytes + 255) & ~(size_t)255; return p;
    };
    unsigned short* esb  = (unsigned short*)alloc(3 * BE_ * 2);
    unsigned short* B0   = (unsigned short*)alloc(3 * BE_ * 2);
    unsigned short* B1   = (unsigned short*)alloc(3 * BE_ * 2);
    unsigned short* WtC  = (unsigned short*)alloc((size_t)12 * 512 * 512 * 2);
    unsigned short* Wt1  = (unsigned short*)alloc((size_t)512 * 256 * 2);
    unsigned short* Wt2  = (unsigned short*)alloc((size_t)256 * 128 * 2);
    float*          mbuf = (float*)alloc(48 * 1024 * 4);
    float*          svb  = (float*)alloc(48 * 32 * 4);
    unsigned short* hsb = B0;
    unsigned short* h1b = B0 + (size_t)B_ * M1_;
    unsigned short* h2b = h1b + (size_t)B_ * M2_;

    // weights -> bf16 transposed [N][K]
    wtrans12_k<<<dim3(16, 16, 12), 256, 0, stream>>>(crossW, mlp1W, WtC);
    wtrans_k<<<dim3( 8, 16), 256, 0, stream>>>(W1, Wt1, 512, 256);
    wtrans_k<<<dim3( 4,  8), 256, 0, stream>>>(W2, Wt2, 256, 128);

    gather_k<<<(NE_ * B_ * F_ * 4) / 256, 256, 0, stream>>>(x, emb, esb);

    // regularization path
    hipMemsetAsync(mbuf, 0, 48 * 1024 * 4, stream);
    pairsum_k<<<dim3(48, 16), 256, 0, stream>>>(esb, mbuf);
    svd_k<<<48, 64, 0, stream>>>(mbuf, svb);
    reg_k<<<1, 128, 0, stream>>>(svb, out);

    // main path: fused cross+mlp1 per branch (96KB dynamic LDS, 1 block/CU)
    branch_k<<<dim3(128, 3), 256, 98304, stream>>>(esb, WtC, crossb, mlp1b, B1);
    sum3_k<<<(B_ * M1_) / (256 * 8), 256, 0, stream>>>(B1, hsb);
    gemm_mfma_k<<<dim3(2, 64), 256, 0, stream>>>(hsb, Wt1, b1, h1b, B_, M2_, M1_);
    gemm_mfma_k<<<dim3(1, 64), 256, 0, stream>>>(h1b, Wt2, b2, h2b, B_, M3_, M2_);
    final_k<<<(B_ * 64) / 256, 256, 0, stream>>>(h2b, W3, b3, out);
}